// Round 9
// baseline (61.263 us; speedup 1.0000x reference)
//
#include <hip/hip_runtime.h>
#include <hip/hip_bf16.h>

#define HH 8
#define SEQL 4096
#define DD 128
#define NBLK 64
#define LOCAL_B 16
#define MBIAS 12.0f

typedef __attribute__((ext_vector_type(8))) short bf16x8;
typedef __attribute__((ext_vector_type(4))) short bf16x4;
typedef __attribute__((ext_vector_type(4))) float f32x4;
typedef unsigned short ushort_t;

typedef const __attribute__((address_space(1))) unsigned int gu32;
typedef __attribute__((address_space(3))) unsigned int lu32;

__device__ __forceinline__ unsigned short f2bf(float x) {
    union { float f; unsigned u; } a; a.f = x;
    unsigned r = a.u + 0x7FFFu + ((a.u >> 16) & 1u);
    return (unsigned short)(r >> 16);
}

__device__ __forceinline__ unsigned cvtpk_bf16(float lo, float hi) {
    unsigned r;
    asm("v_cvt_pk_bf16_f32 %0, %1, %2" : "=v"(r) : "v"(lo), "v"(hi));
    return r;
}

__device__ __forceinline__ f32x4 mfma16(bf16x4 a, bf16x4 b, f32x4 c) {
#if __has_builtin(__builtin_amdgcn_mfma_f32_16x16x16bf16_1k)
    return __builtin_amdgcn_mfma_f32_16x16x16bf16_1k(a, b, c, 0, 0, 0);
#else
    asm("v_mfma_f32_16x16x16_bf16 %0, %1, %2, %0" : "+v"(c) : "v"(a), "v"(b));
    return c;
#endif
}

__device__ __forceinline__ void gload16(const void* src, void* ldsdst) {
    __builtin_amdgcn_global_load_lds((gu32*)src, (lu32*)ldsdst, 16, 0, 0);
}

// ---------------- fused prepass: K f32->bf16 flat; V f32 [H][S][D] -> bf16 Vt [H][D][S] ----------------
#define T_STR 136
__global__ void prep(const float* __restrict__ k, const float* __restrict__ v,
                     ushort_t* __restrict__ kb, ushort_t* __restrict__ vt) {
    __shared__ ushort_t t[64 * T_STR];
    int bid = blockIdx.x;
    int tid = threadIdx.x;
    if (bid < 2048) {
        int idx = (bid * 256 + tid) * 8;
        const float4* s = (const float4*)(k + idx);
        float4 a = s[0], b = s[1];
        union { bf16x8 v8; ushort_t u[8]; } p;
        p.u[0] = f2bf(a.x); p.u[1] = f2bf(a.y); p.u[2] = f2bf(a.z); p.u[3] = f2bf(a.w);
        p.u[4] = f2bf(b.x); p.u[5] = f2bf(b.y); p.u[6] = f2bf(b.z); p.u[7] = f2bf(b.w);
        *(bf16x8*)(kb + idx) = p.v8;
        return;
    }
    int g = bid - 2048;
    int h  = g >> 6;
    int sb = g & 63;
    const float* vp = v + ((size_t)h * SEQL + sb * 64) * DD;
    {
        int col = (tid & 15) * 8;
        #pragma unroll
        for (int it = 0; it < 4; ++it) {
            int row = it * 16 + (tid >> 4);
            const float4* s = (const float4*)(vp + row * DD + col);
            float4 a = s[0], b = s[1];
            union { bf16x8 v8; ushort_t u[8]; } p;
            p.u[0] = f2bf(a.x); p.u[1] = f2bf(a.y); p.u[2] = f2bf(a.z); p.u[3] = f2bf(a.w);
            p.u[4] = f2bf(b.x); p.u[5] = f2bf(b.y); p.u[6] = f2bf(b.z); p.u[7] = f2bf(b.w);
            *(bf16x8*)&t[row * T_STR + col] = p.v8;
        }
    }
    __syncthreads();
    {
        int d = tid >> 1, seg = tid & 1;
        ushort_t* dst = vt + ((size_t)h * DD + d) * SEQL + sb * 64 + seg * 32;
        #pragma unroll
        for (int i = 0; i < 4; ++i) {
            union { bf16x8 v8; ushort_t u[8]; } o;
            #pragma unroll
            for (int e = 0; e < 8; ++e)
                o.u[e] = t[(seg * 32 + i * 8 + e) * T_STR + d];
            *(bf16x8*)(dst + i * 8) = o.v8;
        }
    }
}

// ---------------- main kernel: 4 waves, wave = 16-k slice x all 64 q; zero-shuffle P ----------------
__global__ __launch_bounds__(256, 2)
void bsattn9(const float* __restrict__ q, const ushort_t* __restrict__ kbuf,
             const ushort_t* __restrict__ vtbuf, const float* __restrict__ scl,
             float* __restrict__ out) {
    const int g  = blockIdx.x;
    const int h  = g & 7;
    const int i0 = g >> 3;
    const int qb = (i0 < 32) ? (63 - i0) : (i0 - 32);
    const int tid = threadIdx.x;
    const int w  = tid >> 6;     // wave = k-slice (16 rows)
    const int l  = tid & 63;
    const int lr = l & 15;
    const int lg = l >> 4;

    __shared__ char smem[65536];
    // K dbuf: [0,32768)     two 16KB tiles (64 rows x 256B, chunk-XOR swizzled)
    // V dbuf: [32768,65536) two 16KB tiles (128 rows x 128B, chunk-XOR swizzled)
    // epilogue reuses smem: lsum[4][64] then two 32KB merge buffers

    const float kappa = scl[0] * 1.44269504088896f;

    const float*    qh = q     + (size_t)h * SEQL * DD;
    const ushort_t* kh = kbuf  + (size_t)h * SEQL * DD;
    const ushort_t* vh = vtbuf + (size_t)h * DD * SEQL;
    float*          oh = out   + (size_t)h * SEQL * DD;

    // Q -> B-fragments for all 4 q-groups (wave-independent), prescaled by kappa
    bf16x8 qf[4][4];
    #pragma unroll
    for (int qg = 0; qg < 4; ++qg) {
        const float* qrow = qh + (size_t)(qb * 64 + qg * 16 + lr) * DD;
        #pragma unroll
        for (int ks = 0; ks < 4; ++ks) {
            const float4* p4 = (const float4*)(qrow + ks * 32 + lg * 8);
            float4 x = p4[0], y = p4[1];
            union { bf16x8 v8; ushort_t u[8]; } pk;
            pk.u[0] = f2bf(x.x * kappa); pk.u[1] = f2bf(x.y * kappa);
            pk.u[2] = f2bf(x.z * kappa); pk.u[3] = f2bf(x.w * kappa);
            pk.u[4] = f2bf(y.x * kappa); pk.u[5] = f2bf(y.y * kappa);
            pk.u[6] = f2bf(y.z * kappa); pk.u[7] = f2bf(y.w * kappa);
            qf[qg][ks] = pk.v8;
        }
    }

    f32x4 oacc[8][4];   // partial O^T (this wave's k-slice): [dt][qg], d=16dt+4lg+j, q=16qg+lr
    #pragma unroll
    for (int dt = 0; dt < 8; ++dt)
        #pragma unroll
        for (int qg = 0; qg < 4; ++qg) oacc[dt][qg] = (f32x4){0.f, 0.f, 0.f, 0.f};
    float lrun[4] = {0.f, 0.f, 0.f, 0.f};

    // swizzled LDS read bases (flip 16384 per iter)
    unsigned kA = (unsigned)((w * 16 + lr) * 256) + (unsigned)((lg * 16) ^ ((lr & 7) << 4));
    unsigned kB = kA ^ 64u;
    unsigned vA = 32768u + (unsigned)(lr * 128) +
                  (unsigned)((((2 * w + (lg >> 1)) ^ (lr & 7)) << 4) + (lg & 1) * 8);
    unsigned kst = 0, vst = 0;

    auto stage = [&](int kb) {
        const char* kbase = (const char*)(kh + (size_t)kb * 64 * DD);
        #pragma unroll
        for (int i = 0; i < 4; ++i) {
            int row = w * 16 + i * 4 + (l >> 4);
            int col = (l & 15) * 16;
            gload16(kbase + row * 256 + (col ^ ((row & 7) << 4)),
                    smem + kst + w * 4096 + i * 1024 + l * 16);
        }
        const char* vbase = (const char*)vh + (size_t)kb * 128;
        #pragma unroll
        for (int i = 0; i < 4; ++i) {
            int d = w * 32 + i * 8 + (l >> 3);
            int c = (l & 7) * 16;
            gload16(vbase + (size_t)d * (SEQL * 2) + (c ^ ((d & 7) << 4)),
                    smem + 32768 + vst + w * 4096 + i * 1024 + l * 16);
        }
        kst ^= 16384u; vst ^= 16384u;
    };

    auto compute = [&](bool diag) {
        // K fragments for this wave's 16-row slice (4 x b128)
        bf16x8 kf0 = *(const bf16x8*)(smem + kA);
        bf16x8 kf1 = *(const bf16x8*)(smem + kB);
        bf16x8 kf2 = *(const bf16x8*)(smem + kA + 128);
        bf16x8 kf3 = *(const bf16x8*)(smem + kB + 128);
        f32x4 sacc[4];
        #pragma unroll
        for (int qg = 0; qg < 4; ++qg)
            sacc[qg] = (f32x4){-MBIAS, -MBIAS, -MBIAS, -MBIAS};
        __builtin_amdgcn_s_setprio(1);
        #pragma unroll
        for (int qg = 0; qg < 4; ++qg) {
            sacc[qg] = __builtin_amdgcn_mfma_f32_16x16x32_bf16(kf0, qf[qg][0], sacc[qg], 0, 0, 0);
            sacc[qg] = __builtin_amdgcn_mfma_f32_16x16x32_bf16(kf1, qf[qg][1], sacc[qg], 0, 0, 0);
            sacc[qg] = __builtin_amdgcn_mfma_f32_16x16x32_bf16(kf2, qf[qg][2], sacc[qg], 0, 0, 0);
            sacc[qg] = __builtin_amdgcn_mfma_f32_16x16x32_bf16(kf3, qf[qg][3], sacc[qg], 0, 0, 0);
        }
        __builtin_amdgcn_s_setprio(0);

        // p = exp2(S^T - M); lane holds P[k=16w+4lg+j][q=16qg+lr] == PV B-fragment layout
        float p[4][4];
        #pragma unroll
        for (int qg = 0; qg < 4; ++qg)
            #pragma unroll
            for (int j = 0; j < 4; ++j)
                p[qg][j] = exp2f(sacc[qg][j]);
        if (diag) {
            #pragma unroll
            for (int qg = 0; qg < 4; ++qg)
                #pragma unroll
                for (int j = 0; j < 4; ++j)
                    if (w * 16 + 4 * lg + j > qg * 16 + lr) p[qg][j] = 0.f;
        }
        bf16x4 pf[4];
        #pragma unroll
        for (int qg = 0; qg < 4; ++qg) {
            lrun[qg] += p[qg][0] + p[qg][1] + p[qg][2] + p[qg][3];
            union { unsigned u[2]; bf16x4 v4; } pk;
            pk.u[0] = cvtpk_bf16(p[qg][0], p[qg][1]);
            pk.u[1] = cvtpk_bf16(p[qg][2], p[qg][3]);
            pf[qg] = pk.v4;
        }

        // O^T partial += Vt[:, k-slice] P[k-slice, :]   (16x16x16, zero shuffle)
        __builtin_amdgcn_s_setprio(1);
        #pragma unroll
        for (int dt = 0; dt < 8; ++dt) {
            bf16x4 vf = *(const bf16x4*)(smem + vA + dt * 2048);
            #pragma unroll
            for (int qg = 0; qg < 4; ++qg)
                oacc[dt][qg] = mfma16(vf, pf[qg], oacc[dt][qg]);
        }
        __builtin_amdgcn_s_setprio(0);
    };

    // iterate active k blocks: verticals, local band, diagonal last
    const int vstart = (7 - h) & 7;
    int lo = qb - (LOCAL_B - 1); if (lo < 0) lo = 0;
    int kb = (vstart <= qb - LOCAL_B) ? vstart : lo;
    stage(kb);
    for (;;) {
        int kn;
        if (kb < lo) { int n = kb + 8; kn = (n <= qb - LOCAL_B) ? n : lo; }
        else if (kb < qb) kn = kb + 1;
        else kn = -1;

        if (kn >= 0) {
            stage(kn);
            asm volatile("s_waitcnt vmcnt(8)" ::: "memory");
        } else {
            asm volatile("s_waitcnt vmcnt(0)" ::: "memory");
        }
        __builtin_amdgcn_sched_barrier(0);
        __builtin_amdgcn_s_barrier();
        __builtin_amdgcn_sched_barrier(0);
        compute(kb == qb);
        __builtin_amdgcn_s_barrier();
        kA ^= 16384u; kB ^= 16384u; vA ^= 16384u;
        if (kn < 0) break;
        kb = kn;
    }

    // ---- epilogue: row sums across k-slices, 4-way O merge, normalize, store ----
    __syncthreads();
    #pragma unroll
    for (int qg = 0; qg < 4; ++qg) {
        lrun[qg] += __shfl_xor(lrun[qg], 16);
        lrun[qg] += __shfl_xor(lrun[qg], 32);
    }
    float* lsumL = (float*)smem;    // [4][64]
    if (lg == 0) {
        #pragma unroll
        for (int qg = 0; qg < 4; ++qg) lsumL[w * 64 + qg * 16 + lr] = lrun[qg];
    }
    __syncthreads();
    float den[4] = {0.f, 0.f, 0.f, 0.f};
    if (w == 0) {
        #pragma unroll
        for (int qg = 0; qg < 4; ++qg) {
            float s = lsumL[qg * 16 + lr] + lsumL[64 + qg * 16 + lr] +
                      lsumL[128 + qg * 16 + lr] + lsumL[192 + qg * 16 + lr];
            den[qg] = 1.0f / s;
        }
    }
    __syncthreads();

    char* mb0 = smem;              // 32KB: [q][d] f32, 512B rows, 16B-chunk XOR (q&7)
    char* mb1 = smem + 32768;
    auto wrbuf = [&](char* b) {
        #pragma unroll
        for (int dt = 0; dt < 8; ++dt)
            #pragma unroll
            for (int qg = 0; qg < 4; ++qg) {
                int qq = qg * 16 + lr;
                *(f32x4*)(b + qq * 512 + (((dt * 4 + lg) ^ (qq & 7)) << 4)) = oacc[dt][qg];
            }
    };
    auto addbuf = [&](char* b) {
        #pragma unroll
        for (int dt = 0; dt < 8; ++dt)
            #pragma unroll
            for (int qg = 0; qg < 4; ++qg) {
                int qq = qg * 16 + lr;
                f32x4 vv = *(const f32x4*)(b + qq * 512 + (((dt * 4 + lg) ^ (qq & 7)) << 4));
                oacc[dt][qg][0] += vv[0]; oacc[dt][qg][1] += vv[1];
                oacc[dt][qg][2] += vv[2]; oacc[dt][qg][3] += vv[3];
            }
    };
    if (w == 2) wrbuf(mb0);
    if (w == 3) wrbuf(mb1);
    __syncthreads();
    if (w == 0) addbuf(mb0);
    if (w == 1) addbuf(mb1);
    __syncthreads();
    if (w == 1) wrbuf(mb0);
    __syncthreads();
    if (w == 0) {
        addbuf(mb0);
        #pragma unroll
        for (int dt = 0; dt < 8; ++dt)
            #pragma unroll
            for (int qg = 0; qg < 4; ++qg) {
                oacc[dt][qg][0] *= den[qg]; oacc[dt][qg][1] *= den[qg];
                oacc[dt][qg][2] *= den[qg]; oacc[dt][qg][3] *= den[qg];
            }
        wrbuf(mb0);
    }
    __syncthreads();
    {
        int qq  = tid >> 2;           // 0..63
        int seg = tid & 3;            // 32 floats each
        float* op = oh + (size_t)(qb * 64 + qq) * DD + seg * 32;
        #pragma unroll
        for (int i = 0; i < 8; ++i) {
            int c = seg * 8 + i;
            f32x4 vv = *(const f32x4*)(mb0 + qq * 512 + ((c ^ (qq & 7)) << 4));
            *(f32x4*)(op + i * 4) = vv;
        }
    }
}

extern "C" void kernel_launch(void* const* d_in, const int* in_sizes, int n_in,
                              void* d_out, int out_size, void* d_ws, size_t ws_size,
                              hipStream_t stream) {
    const float* q   = (const float*)d_in[0];
    const float* k   = (const float*)d_in[1];
    const float* v   = (const float*)d_in[2];
    const float* scl = (const float*)d_in[3];
    float* out = (float*)d_out;

    ushort_t* Kb = (ushort_t*)d_ws;                          // 8 MB bf16 K
    ushort_t* Vt = Kb + (size_t)HH * SEQL * DD;              // 8 MB bf16 V^T

    prep<<<dim3(2048 + HH * 64), dim3(256), 0, stream>>>(k, v, Kb, Vt);
    bsattn9<<<dim3(HH * NBLK), dim3(256), 0, stream>>>(q, Kb, Vt, scl, out);
}